// Round 2
// baseline (258.602 us; speedup 1.0000x reference)
//
#include <hip/hip_runtime.h>

#define LOGZERO -10000000000.0f

// Problem constants (fixed shapes from the reference)
constexpr int Bc    = 8;      // batch
constexpr int Tc    = 500;    // time
constexpr int Oc    = 10000;  // vocab
constexpr int NBH   = 64;     // B * W hyps
constexpr int NHYP  = 8;      // hyps per batch (NBH / Bc)
constexpr int SNUM  = 200;    // scoring ids per hyp
constexpr int BLANK = 0;
constexpr int EOSID = 2;

constexpr int TC     = 4;                  // t-rows per block
constexpr int NCHUNK = (Tc + TC - 1) / TC; // 125
constexpr int NSCORE = Bc * NCHUNK;        // 1000 scoring blocks
constexpr int NP     = 7;                  // pairs per thread: ceil(1600/256)
constexpr int NV4    = Oc / 4;             // 2500 float4 per row
constexpr int FULLI  = NV4 / 256;          // 9 full staging iters
constexpr int REMT   = NV4 - FULLI * 256;  // 196 threads in last iter

__device__ __forceinline__ float logaddexp_f(float a, float b) {
    float m = fmaxf(a, b);
    return m + log1pf(expf(-fabsf(a - b)));
}

// Fused kernel: blocks [0, NSCORE) accumulate sum_t exp(phi + x) into acc;
// blocks [NSCORE, NSCORE+NBH) write the dense output sweep (LOGZERO/eos - s_prev).
__global__ __launch_bounds__(256) void ctc_main_kernel(
    const float* __restrict__ x,            // (B, T, O)
    const float* __restrict__ r_prev,       // (T, 2, NBH)
    const float* __restrict__ s_prev,       // (NBH, O)
    const int*   __restrict__ xlens,        // (B,)
    const int*   __restrict__ last_ids,     // (NBH,)
    const int*   __restrict__ scoring_ids,  // (NBH, SNUM)
    const int*   __restrict__ olen_p,       // (1,)
    float*       __restrict__ acc_out,      // (NBH, SNUM), pre-zeroed
    float*       __restrict__ out)          // (NBH, O)
{
    const int blk = blockIdx.x;
    const int tid = threadIdx.x;

    if (blk >= NSCORE) {
        // ---- sweep role: out[h, :] = (LOGZERO | eos at EOS) - s_prev[h, :] ----
        const int h = blk - NSCORE;
        const int b = h >> 3;
        const int end = xlens[b] - 1;
        const float r0 = r_prev[(size_t)end * (2 * NBH) + h];
        const float r1 = r_prev[(size_t)end * (2 * NBH) + NBH + h];
        const float eos = logaddexp_f(r0, r1);

        const float4* sp4  = (const float4*)(s_prev + (size_t)h * Oc);
        float4*       out4 = (float4*)(out + (size_t)h * Oc);
        for (int idx = tid; idx < NV4; idx += 256) {
            float4 s = sp4[idx];
            int o = idx * 4;
            float4 v;
            v.x = ((o + 0 == EOSID) ? eos : LOGZERO) - s.x;
            v.y = ((o + 1 == EOSID) ? eos : LOGZERO) - s.y;
            v.z = ((o + 2 == EOSID) ? eos : LOGZERO) - s.z;
            v.w = ((o + 3 == EOSID) ? eos : LOGZERO) - s.w;
            out4[idx] = v;
        }
        return;
    }

    // ---- score role ----
    // c-major mapping: consecutive blocks span all 8 batches (load balance),
    // and the likely-early-exit high-t chunks are dispatched last (backfill).
    const int c  = blk >> 3;
    const int b  = blk & 7;
    const int t0 = c * TC;

    const int ol    = olen_p[0];
    const int start = (ol > 1) ? ol : 1;
    const int tlo   = (ol == 0) ? 0 : start;   // ol==0 adds the t=0 term (r0 = x_[0,0], phi=0)
    int xlen = xlens[b];
    if (xlen > Tc) xlen = Tc;
    const int lo = (t0 > tlo) ? t0 : tlo;
    const int hi = ((t0 + TC) < xlen) ? (t0 + TC) : xlen;
    if (lo >= hi) return;
    const int nt = hi - lo;

    __shared__ __align__(16) float xrow[Oc];
    __shared__ float pnoL[TC][NHYP];
    __shared__ float phitL[TC][NHYP];

    // Precompute phi for all (t, hyp) of this block before the main loop.
    if (tid < nt * NHYP) {
        const int ti = tid >> 3;
        const int j  = tid & 7;
        const int t  = lo + ti;
        if (t == 0) {
            pnoL[ti][j]  = 0.0f;   // t=0 term uses r0 = x_ directly -> phi = 0
            phitL[ti][j] = 0.0f;
        } else {
            const int h = b * NHYP + j;
            const float r0 = r_prev[(size_t)(t - 1) * (2 * NBH) + h];
            const float r1 = r_prev[(size_t)(t - 1) * (2 * NBH) + NBH + h];
            phitL[ti][j] = r1;
            pnoL[ti][j]  = logaddexp_f(r0, r1);
        }
    }

    // Per-thread pair setup (pairs p = tid + i*256 over 8 hyps x 200 ids)
    int   sid[NP];
    int   jj[NP];
    bool  hit[NP];
    float acc[NP];
#pragma unroll
    for (int i = 0; i < NP; ++i) {
        acc[i] = 0.0f;
        int p = tid + i * 256;
        if (p < NHYP * SNUM) {
            int j = p / SNUM;
            int k = p - j * SNUM;
            int h = b * NHYP + j;
            int s = scoring_ids[h * SNUM + k];
            sid[i] = s;
            jj[i]  = j;
            hit[i] = (s == last_ids[h]);
        } else {
            sid[i] = 0; jj[i] = 0; hit[i] = false;
        }
    }

    for (int t = lo, ti = 0; t < hi; ++t, ++ti) {
        // Stage x[b, t, :] into LDS: 10-deep register-buffered, fully unrolled
        // so all loads are in flight before any ds_write waits.
        const float4* row4 = (const float4*)(x + (size_t)(b * Tc + t) * Oc);
        float4* x4 = (float4*)xrow;
        float4 buf[FULLI + 1];
#pragma unroll
        for (int i = 0; i < FULLI; ++i) buf[i] = row4[tid + i * 256];
        if (tid < REMT) buf[FULLI] = row4[tid + FULLI * 256];
#pragma unroll
        for (int i = 0; i < FULLI; ++i) x4[tid + i * 256] = buf[i];
        if (tid < REMT) x4[tid + FULLI * 256] = buf[FULLI];
        __syncthreads();

#pragma unroll
        for (int i = 0; i < NP; ++i) {
            int p = tid + i * 256;
            if (p < NHYP * SNUM) {
                float ph = hit[i] ? phitL[ti][jj[i]] : pnoL[ti][jj[i]];
                acc[i] += expf(ph + xrow[sid[i]]);
            }
        }
        __syncthreads();
    }

#pragma unroll
    for (int i = 0; i < NP; ++i) {
        int p = tid + i * 256;
        if (p < NHYP * SNUM && acc[i] != 0.0f) {
            int j = jj[i];
            int k = p - j * SNUM;
            int h = b * NHYP + j;
            atomicAdd(&acc_out[h * SNUM + k], acc[i]);
        }
    }
}

// Scatter kernel: out[h, ids[h,k]] = log(acc[h,k]) - s_prev (skip BLANK/EOS).
__global__ __launch_bounds__(256) void ctc_scatter_kernel(
    const float* __restrict__ s_prev,       // (NBH, O)
    const int*   __restrict__ scoring_ids,  // (NBH, SNUM)
    const float* __restrict__ acc_in,       // (NBH, SNUM)
    float*       __restrict__ out)          // (NBH, O)
{
    const int h   = blockIdx.x;
    const int tid = threadIdx.x;
    if (tid < SNUM) {
        int o = scoring_ids[h * SNUM + tid];
        if (o != BLANK && o != EOSID) {
            float sum = acc_in[h * SNUM + tid];
            sum = fmaxf(sum, 1e-37f);  // guard log(0); unreachable with real data
            float psi = logf(sum);
            out[(size_t)h * Oc + o] = psi - s_prev[(size_t)h * Oc + o];
        }
    }
}

extern "C" void kernel_launch(void* const* d_in, const int* in_sizes, int n_in,
                              void* d_out, int out_size, void* d_ws, size_t ws_size,
                              hipStream_t stream) {
    const float* x           = (const float*)d_in[0];
    const float* r_prev      = (const float*)d_in[1];
    const float* s_prev      = (const float*)d_in[2];
    const int*   xlens       = (const int*)d_in[3];
    const int*   last_ids    = (const int*)d_in[4];
    const int*   scoring_ids = (const int*)d_in[5];
    const int*   olen        = (const int*)d_in[6];
    float* out = (float*)d_out;
    float* acc = (float*)d_ws;  // NBH*SNUM floats = 51.2 KB

    hipMemsetAsync(acc, 0, NBH * SNUM * sizeof(float), stream);
    ctc_main_kernel<<<NSCORE + NBH, 256, 0, stream>>>(
        x, r_prev, s_prev, xlens, last_ids, scoring_ids, olen, acc, out);
    ctc_scatter_kernel<<<NBH, 256, 0, stream>>>(
        s_prev, scoring_ids, acc, out);
}

// Round 4
// 242.510 us; speedup vs baseline: 1.0664x; 1.0664x over previous
//
#include <hip/hip_runtime.h>

#define LOGZERO -10000000000.0f

// Problem constants (fixed shapes from the reference)
constexpr int Bc    = 8;      // batch
constexpr int Tc    = 500;    // time
constexpr int Oc    = 10000;  // vocab
constexpr int NBH   = 64;     // B * W hyps
constexpr int NHYP  = 8;      // hyps per batch (NBH / Bc)
constexpr int SNUM  = 200;    // scoring ids per hyp
constexpr int BLANK = 0;
constexpr int EOSID = 2;

constexpr int TC     = 4;                  // t-rows per block
constexpr int NCHUNK = (Tc + TC - 1) / TC; // 125
constexpr int NSCORE = Bc * NCHUNK;        // 1000 scoring blocks
constexpr int NPAIR  = NHYP * SNUM;        // 1600 (h,k) pairs per batch
constexpr int NP     = 7;                  // pairs per thread: ceil(1600/256)
constexpr int NV4    = Oc / 4;             // 2500 float4 per row

__device__ __forceinline__ float logaddexp_f(float a, float b) {
    float m = fmaxf(a, b);
    return m + log1pf(expf(-fabsf(a - b)));
}

// Fused kernel.
//   blocks [0, NSCORE): score role — accumulate sum_t exp(phi + x) over this
//     block's TC t-rows into a PRIVATE partial slice part[c][b*8..b*8+8][0..200)
//     (contiguous 1600 floats, coalesced stores, NO atomics). Inactive blocks
//     zero their slice, so no memset dispatch is needed.
//   blocks [NSCORE, NSCORE+NBH): sweep role — out[h,:] = (LOGZERO|eos) - s_prev.
__global__ __launch_bounds__(256, 4) void ctc_main_kernel(
    const float* __restrict__ x,            // (B, T, O)
    const float* __restrict__ r_prev,       // (T, 2, NBH)
    const float* __restrict__ s_prev,       // (NBH, O)
    const int*   __restrict__ xlens,        // (B,)
    const int*   __restrict__ last_ids,     // (NBH,)
    const int*   __restrict__ scoring_ids,  // (NBH, SNUM)
    const int*   __restrict__ olen_p,       // (1,)
    float*       __restrict__ part,         // (NCHUNK, NBH, SNUM) partials
    float*       __restrict__ out)          // (NBH, O)
{
    const int blk = blockIdx.x;
    const int tid = threadIdx.x;

    if (blk >= NSCORE) {
        // ---- sweep role ----
        const int h = blk - NSCORE;
        const int b = h >> 3;
        const int end = xlens[b] - 1;
        const float r0 = r_prev[(size_t)end * (2 * NBH) + h];
        const float r1 = r_prev[(size_t)end * (2 * NBH) + NBH + h];
        const float eos = logaddexp_f(r0, r1);

        const float4* sp4  = (const float4*)(s_prev + (size_t)h * Oc);
        float4*       out4 = (float4*)(out + (size_t)h * Oc);
        for (int idx = tid; idx < NV4; idx += 256) {
            float4 s = sp4[idx];
            int o = idx * 4;
            float4 v;
            v.x = ((o + 0 == EOSID) ? eos : LOGZERO) - s.x;
            v.y = ((o + 1 == EOSID) ? eos : LOGZERO) - s.y;
            v.z = ((o + 2 == EOSID) ? eos : LOGZERO) - s.z;
            v.w = ((o + 3 == EOSID) ? eos : LOGZERO) - s.w;
            out4[idx] = v;
        }
        return;
    }

    // ---- score role ----
    // c-major mapping: consecutive blocks span all 8 batches (CU load balance),
    // high-t (likely early-exit) chunks dispatch last (natural backfill).
    const int c  = blk >> 3;
    const int b  = blk & 7;
    const int t0 = c * TC;

    float* __restrict__ myPart = part + ((size_t)c * NBH + b * NHYP) * SNUM; // 1600 floats

    const int ol    = olen_p[0];
    const int start = (ol > 1) ? ol : 1;
    const int tlo   = (ol == 0) ? 0 : start;   // ol==0 adds the t=0 term (phi = 0)
    int xlen = xlens[b];
    if (xlen > Tc) xlen = Tc;
    const int lo = (t0 > tlo) ? t0 : tlo;
    const int hi = ((t0 + TC) < xlen) ? (t0 + TC) : xlen;
    if (lo >= hi) {
        // inactive: zero the private slice (replaces the global memset)
        for (int p = tid; p < NPAIR; p += 256) myPart[p] = 0.0f;
        return;
    }
    const int nt = hi - lo;

    __shared__ __align__(16) float xrow[Oc];
    __shared__ float phiL[2 * TC * NHYP];   // [sel][ti][j]: sel 0 = no-hit, 1 = hit

    // Precompute phi for all (t, hyp) of this block.
    if (tid < nt * NHYP) {
        const int ti = tid >> 3;
        const int j  = tid & 7;
        const int t  = lo + ti;
        if (t == 0) {
            phiL[ti * NHYP + j]              = 0.0f;  // t=0 term: phi = 0
            phiL[TC * NHYP + ti * NHYP + j]  = 0.0f;
        } else {
            const int h = b * NHYP + j;
            const float r0 = r_prev[(size_t)(t - 1) * (2 * NBH) + h];
            const float r1 = r_prev[(size_t)(t - 1) * (2 * NBH) + NBH + h];
            phiL[ti * NHYP + j]             = logaddexp_f(r0, r1);
            phiL[TC * NHYP + ti * NHYP + j] = r1;
        }
    }

    // Per-thread pair setup (pairs p = tid + i*256 over 8 hyps x 200 ids)
    int   sid[NP];
    int   hoff[NP];   // flattened phi index base: hit*TC*NHYP + j
    float acc[NP];
#pragma unroll
    for (int i = 0; i < NP; ++i) {
        acc[i] = 0.0f;
        int p = tid + i * 256;
        if (p < NPAIR) {
            int j = p / SNUM;
            int k = p - j * SNUM;
            int h = b * NHYP + j;
            int s = scoring_ids[h * SNUM + k];
            sid[i]  = s;
            hoff[i] = ((s == last_ids[h]) ? TC * NHYP : 0) + j;
        } else {
            sid[i] = 0; hoff[i] = 0;
        }
    }

    for (int t = lo, ti = 0; t < hi; ++t, ++ti) {
        // Stage x[b, t, :] into LDS, coalesced float4 (simple loop — low VGPR)
        const float4* row4 = (const float4*)(x + (size_t)(b * Tc + t) * Oc);
        float4* x4 = (float4*)xrow;
        for (int idx = tid; idx < NV4; idx += 256) {
            x4[idx] = row4[idx];
        }
        __syncthreads();

        const int tb = ti * NHYP;
#pragma unroll
        for (int i = 0; i < NP; ++i) {
            int p = tid + i * 256;
            if (p < NPAIR) {
                acc[i] += expf(phiL[hoff[i] + tb] + xrow[sid[i]]);
            }
        }
        __syncthreads();
    }

    // Write private partials (coalesced, no atomics)
#pragma unroll
    for (int i = 0; i < NP; ++i) {
        int p = tid + i * 256;
        if (p < NPAIR) myPart[p] = acc[i];
    }
}

// Reduce partials over c and scatter into out (skip BLANK/EOS).
__global__ __launch_bounds__(256) void ctc_reduce_scatter_kernel(
    const float* __restrict__ s_prev,       // (NBH, O)
    const int*   __restrict__ scoring_ids,  // (NBH, SNUM)
    const float* __restrict__ part,         // (NCHUNK, NBH, SNUM)
    float*       __restrict__ out)          // (NBH, O)
{
    const int h   = blockIdx.x;
    const int tid = threadIdx.x;
    if (tid < SNUM) {
        float sum = 0.0f;
        const float* p = part + (size_t)h * SNUM + tid;
#pragma unroll 5
        for (int c = 0; c < NCHUNK; ++c) {
            sum += p[(size_t)c * NBH * SNUM];
        }
        int o = scoring_ids[h * SNUM + tid];
        if (o != BLANK && o != EOSID) {
            sum = fmaxf(sum, 1e-37f);  // guard log(0); unreachable with real data
            out[(size_t)h * Oc + o] = logf(sum) - s_prev[(size_t)h * Oc + o];
        }
    }
}

extern "C" void kernel_launch(void* const* d_in, const int* in_sizes, int n_in,
                              void* d_out, int out_size, void* d_ws, size_t ws_size,
                              hipStream_t stream) {
    const float* x           = (const float*)d_in[0];
    const float* r_prev      = (const float*)d_in[1];
    const float* s_prev      = (const float*)d_in[2];
    const int*   xlens       = (const int*)d_in[3];
    const int*   last_ids    = (const int*)d_in[4];
    const int*   scoring_ids = (const int*)d_in[5];
    const int*   olen        = (const int*)d_in[6];
    float* out  = (float*)d_out;
    float* part = (float*)d_ws;  // NCHUNK*NBH*SNUM floats = 6.4 MB

    ctc_main_kernel<<<NSCORE + NBH, 256, 0, stream>>>(
        x, r_prev, s_prev, xlens, last_ids, scoring_ids, olen, part, out);
    ctc_reduce_scatter_kernel<<<NBH, 256, 0, stream>>>(
        s_prev, scoring_ids, part, out);
}